// Round 4
// baseline (3261.806 us; speedup 1.0000x reference)
//
#include <hip/hip_runtime.h>
#include <math.h>

#define NGRAPH 500
#define MP_STEPS 6
#define S2S_STEPS 6
#define S2S_CAP 128

typedef _Float16 h8 __attribute__((ext_vector_type(8)));
typedef float f4 __attribute__((ext_vector_type(4)));

__device__ __forceinline__ float sigmoidf_(float v){ return 1.0f/(1.0f + expf(-v)); }

// ---------------- generic zero fill ----------------
__global__ void k_zero(float* __restrict__ p, int n){
  int i = blockIdx.x*256 + threadIdx.x;
  if(i < n) p[i] = 0.f;
}

// ---------------- initial node embedding: x = relu(nf @ lin0_W + b) ----------------
__global__ void k_lin0(const float* __restrict__ nf, const float* __restrict__ W,
                       const float* __restrict__ b, float* __restrict__ x, int N){
  int n = blockIdx.x*4 + (threadIdx.x >> 6);
  int d = threadIdx.x & 63;
  if(n >= N) return;
  float acc = b[d];
#pragma unroll
  for(int i=0;i<15;i++) acc = fmaf(nf[n*15+i], W[i*64+d], acc);
  x[n*64+d] = fmaxf(acc, 0.0f);
}

// ---------------- edge hidden: he_h[e][0..127] = relu(ef@W1+b1), [128]=1, [129..159]=0 ----
__global__ void k_edgeh(const float* __restrict__ ef, const float* __restrict__ W1,
                        const float* __restrict__ b1, _Float16* __restrict__ he, int E){
  int e = blockIdx.x;
  int h = threadIdx.x;   // block 192
  if(e >= E || h >= 160) return;
  float v;
  if(h < 128){
    float acc = b1[h];
#pragma unroll
    for(int i=0;i<5;i++) acc = fmaf(ef[e*5+i], W1[i*128+h], acc);
    v = fmaxf(acc, 0.f);
  } else {
    v = (h == 128) ? 1.0f : 0.0f;
  }
  he[(size_t)e*160 + h] = (_Float16)v;
}

// ---------------- W2T[n][k] (f16): k<128 -> em_W2[k][n]; k==128 -> b2[n]; else 0 ----------
__global__ void k_prepW2(const float* __restrict__ W2, const float* __restrict__ b2,
                         _Float16* __restrict__ W2T){
  int idx = blockIdx.x*256 + threadIdx.x;
  if(idx >= 4096*160) return;
  int n = idx / 160, k = idx % 160;
  float v = (k < 128) ? W2[(size_t)k*4096 + n] : ((k == 128) ? b2[n] : 0.f);
  W2T[idx] = (_Float16)v;
}

// ---------------- fused message: agg[dst[e]] += x[src[e]] . (he[e] @ W2') ----------------
// Block = 64 edges, 4 waves sharing the i-loop; wave w owns output cols [16w,16w+16).
// Register double-buffered B-frag prefetch; fp32 x-multiply; register scatter.
__global__ __launch_bounds__(256, 4) void k_fmsg(
    const _Float16* __restrict__ he,   // [E][160]
    const _Float16* __restrict__ W2T,  // [4096][160]
    const float* __restrict__ x,       // [N][64]
    const int* __restrict__ src, const int* __restrict__ dst,
    float* __restrict__ agg, int E)
{
  __shared__ _Float16 hs[64*160];
  __shared__ float xsT[64*68];
  __shared__ int ds_dst[64];
  const int tid  = threadIdx.x;
  const int wave = tid >> 6;
  const int lane = tid & 63;
  const int quad = lane >> 4;
  const int l15  = lane & 15;
  const int e0   = blockIdx.x * 64;

  for(int t = tid; t < 1280; t += 256){
    int r = t / 20, c = t % 20;
    uint4 v = make_uint4(0,0,0,0);
    if(e0 + r < E) v = *(const uint4*)&he[(size_t)(e0+r)*160 + c*8];
    *(uint4*)&hs[r*160 + c*8] = v;
  }
  {
    int j = tid >> 2, qc = tid & 3;
    int sj = (e0 + j < E) ? src[e0 + j] : 0;
    const float4* xr = (const float4*)(x + (size_t)sj*64);
#pragma unroll
    for(int k=0;k<4;k++){
      float4 v = xr[qc*4 + k];
      int ib = qc*16 + k*4;
      xsT[(ib+0)*68 + j] = v.x;
      xsT[(ib+1)*68 + j] = v.y;
      xsT[(ib+2)*68 + j] = v.z;
      xsT[(ib+3)*68 + j] = v.w;
    }
  }
  if(tid < 64) ds_dst[tid] = (e0 + tid < E) ? dst[e0 + tid] : 0;
  __syncthreads();

  h8 af[4][5];
#pragma unroll
  for(int mt=0;mt<4;mt++)
#pragma unroll
    for(int ks=0;ks<5;ks++)
      af[mt][ks] = *(const h8*)&hs[(mt*16 + l15)*160 + ks*32 + (quad<<3)];

  const _Float16* bbase = W2T + ((size_t)(wave*16 + l15))*160 + (quad<<3);
  h8 bf[5], bn[5];
#pragma unroll
  for(int ks=0;ks<5;ks++) bf[ks] = *(const h8*)(bbase + ks*32);

  f4 macc[4];
#pragma unroll
  for(int mt=0;mt<4;mt++) macc[mt] = (f4){0.f,0.f,0.f,0.f};

#pragma unroll 2
  for(int i=0;i<64;i++){
    if(i < 63){
      const _Float16* nb = bbase + (size_t)(i+1)*64*160;
#pragma unroll
      for(int ks=0;ks<5;ks++) bn[ks] = *(const h8*)(nb + ks*32);
    }
    f4 g0 = (f4){0.f,0.f,0.f,0.f}, g1 = g0, g2 = g0, g3 = g0;
#pragma unroll
    for(int ks=0;ks<5;ks++){
      g0 = __builtin_amdgcn_mfma_f32_16x16x32_f16(af[0][ks], bf[ks], g0, 0, 0, 0);
      g1 = __builtin_amdgcn_mfma_f32_16x16x32_f16(af[1][ks], bf[ks], g1, 0, 0, 0);
      g2 = __builtin_amdgcn_mfma_f32_16x16x32_f16(af[2][ks], bf[ks], g2, 0, 0, 0);
      g3 = __builtin_amdgcn_mfma_f32_16x16x32_f16(af[3][ks], bf[ks], g3, 0, 0, 0);
    }
    f4 x0 = *(const f4*)&xsT[i*68 +  0 + (quad<<2)];
    f4 x1 = *(const f4*)&xsT[i*68 + 16 + (quad<<2)];
    f4 x2 = *(const f4*)&xsT[i*68 + 32 + (quad<<2)];
    f4 x3 = *(const f4*)&xsT[i*68 + 48 + (quad<<2)];
    macc[0] += x0 * g0;
    macc[1] += x1 * g1;
    macc[2] += x2 * g2;
    macc[3] += x3 * g3;
#pragma unroll
    for(int ks=0;ks<5;ks++) bf[ks] = bn[ks];
  }

  const int col = wave*16 + l15;
#pragma unroll
  for(int mt=0;mt<4;mt++){
#pragma unroll
    for(int r=0;r<4;r++){
      int edge = mt*16 + (quad<<2) + r;
      if(e0 + edge < E)
        atomicAdd(&agg[(size_t)ds_dst[edge]*64 + col], macc[mt][r]);
    }
  }
}

// ---------------- GRU: 32 nodes/block ----------------
__global__ __launch_bounds__(256) void k_gru2(
    float* __restrict__ x, float* __restrict__ agg, const float* __restrict__ cb,
    const float* __restrict__ WihT, const float* __restrict__ WhhT,   // [64][192]
    const float* __restrict__ bih, const float* __restrict__ bhh, int N)
{
  __shared__ float ms[32*64], hs2[32*64];
  const int tid = threadIdx.x;
  const int n0 = blockIdx.x*32;
  for(int t=tid; t<2048; t+=256){
    int n = n0 + (t>>6), d = t&63;
    float mv=0.f, hv=0.f;
    if(n < N){
      mv = fmaxf(agg[(size_t)n*64+d] + cb[d], 0.f);
      agg[(size_t)n*64+d] = 0.f;
      hv = x[(size_t)n*64+d];
    }
    ms[t]=mv; hs2[t]=hv;
  }
  __syncthreads();
  const int gx = tid & 31, ng = tid >> 5;
  float ar[4][2]={{0}}, az[4][2]={{0}}, anx[4][2]={{0}}, anh[4][2]={{0}};
#pragma unroll 4
  for(int k=0;k<64;k++){
    float wi0=WihT[k*192+gx],     wi1=WihT[k*192+gx+32];
    float wi2=WihT[k*192+gx+64],  wi3=WihT[k*192+gx+96];
    float wi4=WihT[k*192+gx+128], wi5=WihT[k*192+gx+160];
    float wh0=WhhT[k*192+gx],     wh1=WhhT[k*192+gx+32];
    float wh2=WhhT[k*192+gx+64],  wh3=WhhT[k*192+gx+96];
    float wh4=WhhT[k*192+gx+128], wh5=WhhT[k*192+gx+160];
#pragma unroll
    for(int j=0;j<4;j++){
      float mk = ms[(ng*4+j)*64+k], hk = hs2[(ng*4+j)*64+k];
      ar[j][0] = fmaf(mk,wi0, fmaf(hk,wh0, ar[j][0]));
      ar[j][1] = fmaf(mk,wi1, fmaf(hk,wh1, ar[j][1]));
      az[j][0] = fmaf(mk,wi2, fmaf(hk,wh2, az[j][0]));
      az[j][1] = fmaf(mk,wi3, fmaf(hk,wh3, az[j][1]));
      anx[j][0]= fmaf(mk,wi4, anx[j][0]);
      anx[j][1]= fmaf(mk,wi5, anx[j][1]);
      anh[j][0]= fmaf(hk,wh4, anh[j][0]);
      anh[j][1]= fmaf(hk,wh5, anh[j][1]);
    }
  }
#pragma unroll
  for(int j=0;j<4;j++){
    int n = n0 + ng*4 + j;
    if(n >= N) continue;
#pragma unroll
    for(int c=0;c<2;c++){
      int d = gx + 32*c;
      float r  = sigmoidf_(ar[j][c] + bih[d]     + bhh[d]);
      float z  = sigmoidf_(az[j][c] + bih[64+d]  + bhh[64+d]);
      float nn = tanhf(anx[j][c] + bih[128+d] + r*(anh[j][c] + bhh[128+d]));
      float hv = hs2[(ng*4+j)*64+d];
      x[(size_t)n*64+d] = (1.f - z)*nn + z*hv;
    }
  }
}

// ---------------- weight transposes ----------------
__global__ void k_tr_gru(const float* __restrict__ Wih, const float* __restrict__ Whh,
                         float* __restrict__ WihT, float* __restrict__ WhhT){
  int idx = blockIdx.x*256 + threadIdx.x;
  if(idx < 192*64){
    int r = idx/64, i = idx%64;
    WihT[i*192 + r] = Wih[idx];
    WhhT[i*192 + r] = Whh[idx];
  }
}

__global__ void k_tr_lstm(const float* __restrict__ w0ih, const float* __restrict__ w0hh,
                          const float* __restrict__ w12ih, const float* __restrict__ w12hh,
                          float* __restrict__ t0ih, float* __restrict__ t0hh,
                          float* __restrict__ t12ih, float* __restrict__ t12hh){
  int idx = blockIdx.x*256 + threadIdx.x;
  if(idx < 256*128){ int r = idx/128, k = idx%128; t0ih[k*256+r] = w0ih[idx]; }
  if(idx < 256*64){ int r = idx/64, k = idx%64; t0hh[k*256+r] = w0hh[idx]; }
  if(idx < 2*256*64){
    int l = idx/(256*64); int rem = idx%(256*64); int r = rem/64, k = rem%64;
    t12ih[l*64*256 + k*256 + r] = w12ih[idx];
    t12hh[l*64*256 + k*256 + r] = w12hh[idx];
  }
}

// ---------------- fused Set2Set + head ----------------
__device__ __forceinline__ int lbound(const int* __restrict__ a, int n, int v){
  int lo=0, hi=n;
  while(lo<hi){ int mid=(lo+hi)>>1; if(a[mid]<v) lo=mid+1; else hi=mid; }
  return lo;
}

template<int IN>
__device__ __forceinline__ void lstm_layer(
    const float* __restrict__ xin, float* __restrict__ hv, float* __restrict__ cv,
    const float* __restrict__ WihT, const float* __restrict__ WhhT,
    const float* __restrict__ bi, const float* __restrict__ bh,
    float* __restrict__ gs, int t)
{
  float a0=0.f,a1=0.f,a2=0.f,a3=0.f;
#pragma unroll
  for(int k=0;k<IN;k+=4){
    a0 = fmaf(xin[k+0], WihT[(k+0)*256+t], a0);
    a1 = fmaf(xin[k+1], WihT[(k+1)*256+t], a1);
    a2 = fmaf(xin[k+2], WihT[(k+2)*256+t], a2);
    a3 = fmaf(xin[k+3], WihT[(k+3)*256+t], a3);
  }
#pragma unroll
  for(int k=0;k<64;k+=4){
    a0 = fmaf(hv[k+0], WhhT[(k+0)*256+t], a0);
    a1 = fmaf(hv[k+1], WhhT[(k+1)*256+t], a1);
    a2 = fmaf(hv[k+2], WhhT[(k+2)*256+t], a2);
    a3 = fmaf(hv[k+3], WhhT[(k+3)*256+t], a3);
  }
  gs[t] = (a0+a1)+(a2+a3) + bi[t] + bh[t];
  __syncthreads();
  if(t < 64){
    float ig = sigmoidf_(gs[t]);
    float fg = sigmoidf_(gs[64+t]);
    float gg = tanhf(gs[128+t]);
    float og = sigmoidf_(gs[192+t]);
    float cn = fg*cv[t] + ig*gg;
    cv[t] = cn;
    hv[t] = og*tanhf(cn);
  }
  __syncthreads();
}

__global__ __launch_bounds__(256) void k_s2s(
    const float* __restrict__ x, const int* __restrict__ gid, int N,
    const float* __restrict__ t0ih, const float* __restrict__ t0hh,
    const float* __restrict__ l0_bih, const float* __restrict__ l0_bhh,
    const float* __restrict__ t12ih, const float* __restrict__ t12hh,
    const float* __restrict__ l12_bih, const float* __restrict__ l12_bhh,
    const float* __restrict__ W1, const float* __restrict__ b1,
    const float* __restrict__ W2, const float* __restrict__ b2,
    float* __restrict__ y)
{
  const int b = blockIdx.x;
  const int t = threadIdx.x;
  const int wave = t >> 6, lane = t & 63;
  __shared__ float xt[S2S_CAP*64];
  __shared__ float hsl[3][64], csl[3][64], qs[128], gs[256];
  __shared__ float ps[S2S_CAP], rop[4*64], wred[4], wsum[4];
  __shared__ int sh_n0, sh_n1;

  if(t == 0) sh_n0 = lbound(gid, N, b);
  if(t == 1) sh_n1 = lbound(gid, N, b+1);
  if(t < 192){ hsl[t>>6][t&63] = 0.f; csl[t>>6][t&63] = 0.f; }
  if(t < 128) qs[t] = 0.f;
  __syncthreads();
  const int n0 = sh_n0, cnt = sh_n1 - sh_n0;
  const int cc = (cnt < S2S_CAP) ? cnt : S2S_CAP;

  // cache node tile in LDS (read x once)
  for(int j = wave; j < cc; j += 4)
    xt[j*64 + lane] = x[(size_t)(n0+j)*64 + lane];
  __syncthreads();

  for(int step=0; step<S2S_STEPS; step++){
    lstm_layer<128>(qs,     hsl[0], csl[0], t0ih,           t0hh,           l0_bih,        l0_bhh,        gs, t);
    lstm_layer<64>(hsl[0],  hsl[1], csl[1], t12ih,          t12hh,          l12_bih,       l12_bhh,       gs, t);
    lstm_layer<64>(hsl[1],  hsl[2], csl[2], t12ih + 64*256, t12hh + 64*256, l12_bih + 256, l12_bhh + 256, gs, t);

    // ---- attention: pass 1 (dot + max), dots cached in ps ----
    float qv = hsl[2][lane];
    float pm = -1e30f;
    for(int j = wave; j < cc; j += 4){
      float p = xt[j*64 + lane] * qv;
#pragma unroll
      for(int o=32;o;o>>=1) p += __shfl_xor(p, o, 64);
      if(lane == 0) ps[j] = p;
      pm = fmaxf(pm, p);
    }
    for(int j = S2S_CAP + wave; j < cnt; j += 4){   // fallback (rare)
      float p = x[(size_t)(n0+j)*64 + lane] * qv;
#pragma unroll
      for(int o=32;o;o>>=1) p += __shfl_xor(p, o, 64);
      pm = fmaxf(pm, p);
    }
    if(lane == 0) wred[wave] = pm;
    __syncthreads();
    float mx = fmaxf(fmaxf(wred[0],wred[1]), fmaxf(wred[2],wred[3]));

    // ---- pass 2: exp/sum/weighted accumulate (LDS only for cached nodes) ----
    float pro = 0.f, pssum = 0.f;
    for(int j = wave; j < cc; j += 4){
      float ex = expf(ps[j] - mx);
      pssum += ex;
      pro = fmaf(ex, xt[j*64 + lane], pro);
    }
    for(int j = S2S_CAP + wave; j < cnt; j += 4){   // fallback (rare)
      float xv = x[(size_t)(n0+j)*64 + lane];
      float p = xv * qv;
#pragma unroll
      for(int o=32;o;o>>=1) p += __shfl_xor(p, o, 64);
      float ex = expf(p - mx);
      pssum += ex;
      pro = fmaf(ex, xv, pro);
    }
    rop[wave*64 + lane] = pro;
    if(lane == 0) wsum[wave] = pssum;
    __syncthreads();
    if(t < 64){
      float tot = wsum[0]+wsum[1]+wsum[2]+wsum[3];
      float inv = (tot > 0.f) ? 1.f/tot : 0.f;
      float rv = (rop[t] + rop[64+t] + rop[128+t] + rop[192+t]) * inv;
      qs[t] = hsl[2][t];
      qs[64+t] = rv;
    }
    __syncthreads();
  }
  // ---- head ----
  if(t < 64){
    float a = b1[t];
#pragma unroll 4
    for(int k=0;k<128;k++) a = fmaf(qs[k], W1[k*64+t], a);
    gs[t] = fmaxf(a, 0.f);
  }
  __syncthreads();
  if(t < 12){
    float o = b2[t];
#pragma unroll 4
    for(int k=0;k<64;k++) o = fmaf(gs[k], W2[k*12+t], o);
    y[b*12+t] = o;
  }
}

extern "C" void kernel_launch(void* const* d_in, const int* in_sizes, int n_in,
                              void* d_out, int out_size, void* d_ws, size_t ws_size,
                              hipStream_t stream) {
  const float* node_feat = (const float*)d_in[0];
  const float* edge_feat = (const float*)d_in[1];
  const int*   src       = (const int*)d_in[2];
  const int*   dst       = (const int*)d_in[3];
  const int*   gid       = (const int*)d_in[4];
  const float* lin0_W = (const float*)d_in[6];
  const float* lin0_b = (const float*)d_in[7];
  const float* em_W1  = (const float*)d_in[8];
  const float* em_b1  = (const float*)d_in[9];
  const float* em_W2  = (const float*)d_in[10];
  const float* em_b2  = (const float*)d_in[11];
  const float* conv_b = (const float*)d_in[12];
  const float* gru_Wih = (const float*)d_in[13];
  const float* gru_Whh = (const float*)d_in[14];
  const float* gru_bih = (const float*)d_in[15];
  const float* gru_bhh = (const float*)d_in[16];
  const float* l0_Wih = (const float*)d_in[17];
  const float* l0_Whh = (const float*)d_in[18];
  const float* l0_bih = (const float*)d_in[19];
  const float* l0_bhh = (const float*)d_in[20];
  const float* l12_Wih = (const float*)d_in[21];
  const float* l12_Whh = (const float*)d_in[22];
  const float* l12_bih = (const float*)d_in[23];
  const float* l12_bhh = (const float*)d_in[24];
  const float* lin1_W = (const float*)d_in[25];
  const float* lin1_b = (const float*)d_in[26];
  const float* lin2_W = (const float*)d_in[27];
  const float* lin2_b = (const float*)d_in[28];
  float* y = (float*)d_out;

  const int N = in_sizes[0] / 15;
  const int E = in_sizes[1] / 5;
  const int B = NGRAPH;

  char* p = (char*)d_ws;
  auto carve = [&](size_t bytes)->char* {
    char* r = p; p += (bytes + 255) & ~(size_t)255; return r;
  };
  _Float16* he_h = (_Float16*)carve((size_t)E*160*2);
  _Float16* W2T  = (_Float16*)carve((size_t)4096*160*2);
  float* x     = (float*)carve((size_t)N*64*4);
  float* agg   = (float*)carve((size_t)N*64*4);
  float* gWihT = (float*)carve(192*64*4);
  float* gWhhT = (float*)carve(192*64*4);
  float* t0ih  = (float*)carve(128*256*4);
  float* t0hh  = (float*)carve(64*256*4);
  float* t12ih = (float*)carve(2*64*256*4);
  float* t12hh = (float*)carve(2*64*256*4);
  (void)ws_size; (void)n_in; (void)out_size;

  // ---- prep ----
  k_lin0<<<(N+3)/4, 256, 0, stream>>>(node_feat, lin0_W, lin0_b, x, N);
  k_edgeh<<<E, 192, 0, stream>>>(edge_feat, em_W1, em_b1, he_h, E);
  k_prepW2<<<(4096*160+255)/256, 256, 0, stream>>>(em_W2, em_b2, W2T);
  k_tr_gru<<<(192*64+255)/256, 256, 0, stream>>>(gru_Wih, gru_Whh, gWihT, gWhhT);
  k_tr_lstm<<<(2*256*64+255)/256, 256, 0, stream>>>(l0_Wih, l0_Whh, l12_Wih, l12_Whh,
                                                    t0ih, t0hh, t12ih, t12hh);
  k_zero<<<(N*64+255)/256, 256, 0, stream>>>(agg, N*64);

  // ---- message passing (k_gru2 zeroes agg for the next step) ----
  const int nblk = (E + 63) / 64;
  for(int s=0; s<MP_STEPS; s++){
    k_fmsg<<<nblk, 256, 0, stream>>>(he_h, W2T, x, src, dst, agg, E);
    k_gru2<<<(N+31)/32, 256, 0, stream>>>(x, agg, conv_b, gWihT, gWhhT, gru_bih, gru_bhh, N);
  }

  // ---- fused set2set + head ----
  k_s2s<<<B, 256, 0, stream>>>(x, gid, N,
                               t0ih, t0hh, l0_bih, l0_bhh,
                               t12ih, t12hh, l12_bih, l12_bhh,
                               lin1_W, lin1_b, lin2_W, lin2_b, y);
}

// Round 5
// 951.227 us; speedup vs baseline: 3.4291x; 3.4291x over previous
//
#include <hip/hip_runtime.h>
#include <math.h>

#define NGRAPH 500
#define MP_STEPS 6
#define S2S_STEPS 6
#define S2S_CAP 128

typedef _Float16 h8 __attribute__((ext_vector_type(8)));
typedef float f4 __attribute__((ext_vector_type(4)));

__device__ __forceinline__ float sigmoidf_(float v){ return 1.0f/(1.0f + expf(-v)); }

// ---------------- generic zero fill ----------------
__global__ void k_zero(float* __restrict__ p, int n){
  int i = blockIdx.x*256 + threadIdx.x;
  if(i < n) p[i] = 0.f;
}

// ---------------- initial node embedding: x = relu(nf @ lin0_W + b) ----------------
__global__ void k_lin0(const float* __restrict__ nf, const float* __restrict__ W,
                       const float* __restrict__ b, float* __restrict__ x, int N){
  int n = blockIdx.x*4 + (threadIdx.x >> 6);
  int d = threadIdx.x & 63;
  if(n >= N) return;
  float acc = b[d];
#pragma unroll
  for(int i=0;i<15;i++) acc = fmaf(nf[n*15+i], W[i*64+d], acc);
  x[n*64+d] = fmaxf(acc, 0.0f);
}

// ---------------- edge hidden: he_h[e][0..127] = relu(ef@W1+b1), [128]=1, [129..159]=0 ----
__global__ void k_edgeh(const float* __restrict__ ef, const float* __restrict__ W1,
                        const float* __restrict__ b1, _Float16* __restrict__ he, int E){
  int e = blockIdx.x;
  int h = threadIdx.x;   // block 192
  if(e >= E || h >= 160) return;
  float v;
  if(h < 128){
    float acc = b1[h];
#pragma unroll
    for(int i=0;i<5;i++) acc = fmaf(ef[e*5+i], W1[i*128+h], acc);
    v = fmaxf(acc, 0.f);
  } else {
    v = (h == 128) ? 1.0f : 0.0f;
  }
  he[(size_t)e*160 + h] = (_Float16)v;
}

// ---------------- W2T[n][k] (f16): k<128 -> em_W2[k][n]; k==128 -> b2[n]; else 0 ----------
__global__ void k_prepW2(const float* __restrict__ W2, const float* __restrict__ b2,
                         _Float16* __restrict__ W2T){
  int idx = blockIdx.x*256 + threadIdx.x;
  if(idx >= 4096*160) return;
  int n = idx / 160, k = idx % 160;
  float v = (k < 128) ? W2[(size_t)k*4096 + n] : ((k == 128) ? b2[n] : 0.f);
  W2T[idx] = (_Float16)v;
}

// ---------------- fused message: agg[dst[e]] += x[src[e]] . (he[e] @ W2') ----------------
// Block = 64 edges, 4 waves sharing the i-loop; wave w owns output cols [16w,16w+16).
// Register double-buffered B-frag prefetch; fp32 x-multiply; register scatter.
// NOTE: needs ~128 arch VGPRs. __launch_bounds__(256,4) forces a 128-cap that the
// compiler cannot meet -> catastrophic scratch spill (R4: FETCH 17.8->875 MB,
// 488us/dispatch). Keep (256,2).
__global__ __launch_bounds__(256, 2) void k_fmsg(
    const _Float16* __restrict__ he,   // [E][160]
    const _Float16* __restrict__ W2T,  // [4096][160]
    const float* __restrict__ x,       // [N][64]
    const int* __restrict__ src, const int* __restrict__ dst,
    float* __restrict__ agg, int E)
{
  __shared__ _Float16 hs[64*160];
  __shared__ float xsT[64*68];
  __shared__ int ds_dst[64];
  const int tid  = threadIdx.x;
  const int wave = tid >> 6;
  const int lane = tid & 63;
  const int quad = lane >> 4;
  const int l15  = lane & 15;
  const int e0   = blockIdx.x * 64;

  for(int t = tid; t < 1280; t += 256){
    int r = t / 20, c = t % 20;
    uint4 v = make_uint4(0,0,0,0);
    if(e0 + r < E) v = *(const uint4*)&he[(size_t)(e0+r)*160 + c*8];
    *(uint4*)&hs[r*160 + c*8] = v;
  }
  {
    int j = tid >> 2, qc = tid & 3;
    int sj = (e0 + j < E) ? src[e0 + j] : 0;
    const float4* xr = (const float4*)(x + (size_t)sj*64);
#pragma unroll
    for(int k=0;k<4;k++){
      float4 v = xr[qc*4 + k];
      int ib = qc*16 + k*4;
      xsT[(ib+0)*68 + j] = v.x;
      xsT[(ib+1)*68 + j] = v.y;
      xsT[(ib+2)*68 + j] = v.z;
      xsT[(ib+3)*68 + j] = v.w;
    }
  }
  if(tid < 64) ds_dst[tid] = (e0 + tid < E) ? dst[e0 + tid] : 0;
  __syncthreads();

  h8 af[4][5];
#pragma unroll
  for(int mt=0;mt<4;mt++)
#pragma unroll
    for(int ks=0;ks<5;ks++)
      af[mt][ks] = *(const h8*)&hs[(mt*16 + l15)*160 + ks*32 + (quad<<3)];

  const _Float16* bbase = W2T + ((size_t)(wave*16 + l15))*160 + (quad<<3);
  h8 bf[5], bn[5];
#pragma unroll
  for(int ks=0;ks<5;ks++) bf[ks] = *(const h8*)(bbase + ks*32);

  f4 macc[4];
#pragma unroll
  for(int mt=0;mt<4;mt++) macc[mt] = (f4){0.f,0.f,0.f,0.f};

#pragma unroll 2
  for(int i=0;i<64;i++){
    if(i < 63){
      const _Float16* nb = bbase + (size_t)(i+1)*64*160;
#pragma unroll
      for(int ks=0;ks<5;ks++) bn[ks] = *(const h8*)(nb + ks*32);
    }
    f4 g0 = (f4){0.f,0.f,0.f,0.f}, g1 = g0, g2 = g0, g3 = g0;
#pragma unroll
    for(int ks=0;ks<5;ks++){
      g0 = __builtin_amdgcn_mfma_f32_16x16x32_f16(af[0][ks], bf[ks], g0, 0, 0, 0);
      g1 = __builtin_amdgcn_mfma_f32_16x16x32_f16(af[1][ks], bf[ks], g1, 0, 0, 0);
      g2 = __builtin_amdgcn_mfma_f32_16x16x32_f16(af[2][ks], bf[ks], g2, 0, 0, 0);
      g3 = __builtin_amdgcn_mfma_f32_16x16x32_f16(af[3][ks], bf[ks], g3, 0, 0, 0);
    }
    f4 x0 = *(const f4*)&xsT[i*68 +  0 + (quad<<2)];
    f4 x1 = *(const f4*)&xsT[i*68 + 16 + (quad<<2)];
    f4 x2 = *(const f4*)&xsT[i*68 + 32 + (quad<<2)];
    f4 x3 = *(const f4*)&xsT[i*68 + 48 + (quad<<2)];
    macc[0] += x0 * g0;
    macc[1] += x1 * g1;
    macc[2] += x2 * g2;
    macc[3] += x3 * g3;
#pragma unroll
    for(int ks=0;ks<5;ks++) bf[ks] = bn[ks];
  }

  const int col = wave*16 + l15;
#pragma unroll
  for(int mt=0;mt<4;mt++){
#pragma unroll
    for(int r=0;r<4;r++){
      int edge = mt*16 + (quad<<2) + r;
      if(e0 + edge < E)
        atomicAdd(&agg[(size_t)ds_dst[edge]*64 + col], macc[mt][r]);
    }
  }
}

// ---------------- GRU: 32 nodes/block ----------------
__global__ __launch_bounds__(256) void k_gru2(
    float* __restrict__ x, float* __restrict__ agg, const float* __restrict__ cb,
    const float* __restrict__ WihT, const float* __restrict__ WhhT,   // [64][192]
    const float* __restrict__ bih, const float* __restrict__ bhh, int N)
{
  __shared__ float ms[32*64], hs2[32*64];
  const int tid = threadIdx.x;
  const int n0 = blockIdx.x*32;
  for(int t=tid; t<2048; t+=256){
    int n = n0 + (t>>6), d = t&63;
    float mv=0.f, hv=0.f;
    if(n < N){
      mv = fmaxf(agg[(size_t)n*64+d] + cb[d], 0.f);
      agg[(size_t)n*64+d] = 0.f;
      hv = x[(size_t)n*64+d];
    }
    ms[t]=mv; hs2[t]=hv;
  }
  __syncthreads();
  const int gx = tid & 31, ng = tid >> 5;
  float ar[4][2]={{0}}, az[4][2]={{0}}, anx[4][2]={{0}}, anh[4][2]={{0}};
#pragma unroll 4
  for(int k=0;k<64;k++){
    float wi0=WihT[k*192+gx],     wi1=WihT[k*192+gx+32];
    float wi2=WihT[k*192+gx+64],  wi3=WihT[k*192+gx+96];
    float wi4=WihT[k*192+gx+128], wi5=WihT[k*192+gx+160];
    float wh0=WhhT[k*192+gx],     wh1=WhhT[k*192+gx+32];
    float wh2=WhhT[k*192+gx+64],  wh3=WhhT[k*192+gx+96];
    float wh4=WhhT[k*192+gx+128], wh5=WhhT[k*192+gx+160];
#pragma unroll
    for(int j=0;j<4;j++){
      float mk = ms[(ng*4+j)*64+k], hk = hs2[(ng*4+j)*64+k];
      ar[j][0] = fmaf(mk,wi0, fmaf(hk,wh0, ar[j][0]));
      ar[j][1] = fmaf(mk,wi1, fmaf(hk,wh1, ar[j][1]));
      az[j][0] = fmaf(mk,wi2, fmaf(hk,wh2, az[j][0]));
      az[j][1] = fmaf(mk,wi3, fmaf(hk,wh3, az[j][1]));
      anx[j][0]= fmaf(mk,wi4, anx[j][0]);
      anx[j][1]= fmaf(mk,wi5, anx[j][1]);
      anh[j][0]= fmaf(hk,wh4, anh[j][0]);
      anh[j][1]= fmaf(hk,wh5, anh[j][1]);
    }
  }
#pragma unroll
  for(int j=0;j<4;j++){
    int n = n0 + ng*4 + j;
    if(n >= N) continue;
#pragma unroll
    for(int c=0;c<2;c++){
      int d = gx + 32*c;
      float r  = sigmoidf_(ar[j][c] + bih[d]     + bhh[d]);
      float z  = sigmoidf_(az[j][c] + bih[64+d]  + bhh[64+d]);
      float nn = tanhf(anx[j][c] + bih[128+d] + r*(anh[j][c] + bhh[128+d]));
      float hv = hs2[(ng*4+j)*64+d];
      x[(size_t)n*64+d] = (1.f - z)*nn + z*hv;
    }
  }
}

// ---------------- weight transposes ----------------
__global__ void k_tr_gru(const float* __restrict__ Wih, const float* __restrict__ Whh,
                         float* __restrict__ WihT, float* __restrict__ WhhT){
  int idx = blockIdx.x*256 + threadIdx.x;
  if(idx < 192*64){
    int r = idx/64, i = idx%64;
    WihT[i*192 + r] = Wih[idx];
    WhhT[i*192 + r] = Whh[idx];
  }
}

__global__ void k_tr_lstm(const float* __restrict__ w0ih, const float* __restrict__ w0hh,
                          const float* __restrict__ w12ih, const float* __restrict__ w12hh,
                          float* __restrict__ t0ih, float* __restrict__ t0hh,
                          float* __restrict__ t12ih, float* __restrict__ t12hh){
  int idx = blockIdx.x*256 + threadIdx.x;
  if(idx < 256*128){ int r = idx/128, k = idx%128; t0ih[k*256+r] = w0ih[idx]; }
  if(idx < 256*64){ int r = idx/64, k = idx%64; t0hh[k*256+r] = w0hh[idx]; }
  if(idx < 2*256*64){
    int l = idx/(256*64); int rem = idx%(256*64); int r = rem/64, k = rem%64;
    t12ih[l*64*256 + k*256 + r] = w12ih[idx];
    t12hh[l*64*256 + k*256 + r] = w12hh[idx];
  }
}

// ---------------- fused Set2Set + head ----------------
__device__ __forceinline__ int lbound(const int* __restrict__ a, int n, int v){
  int lo=0, hi=n;
  while(lo<hi){ int mid=(lo+hi)>>1; if(a[mid]<v) lo=mid+1; else hi=mid; }
  return lo;
}

template<int IN>
__device__ __forceinline__ void lstm_layer(
    const float* __restrict__ xin, float* __restrict__ hv, float* __restrict__ cv,
    const float* __restrict__ WihT, const float* __restrict__ WhhT,
    const float* __restrict__ bi, const float* __restrict__ bh,
    float* __restrict__ gs, int t)
{
  float a0=0.f,a1=0.f,a2=0.f,a3=0.f;
#pragma unroll
  for(int k=0;k<IN;k+=4){
    a0 = fmaf(xin[k+0], WihT[(k+0)*256+t], a0);
    a1 = fmaf(xin[k+1], WihT[(k+1)*256+t], a1);
    a2 = fmaf(xin[k+2], WihT[(k+2)*256+t], a2);
    a3 = fmaf(xin[k+3], WihT[(k+3)*256+t], a3);
  }
#pragma unroll
  for(int k=0;k<64;k+=4){
    a0 = fmaf(hv[k+0], WhhT[(k+0)*256+t], a0);
    a1 = fmaf(hv[k+1], WhhT[(k+1)*256+t], a1);
    a2 = fmaf(hv[k+2], WhhT[(k+2)*256+t], a2);
    a3 = fmaf(hv[k+3], WhhT[(k+3)*256+t], a3);
  }
  gs[t] = (a0+a1)+(a2+a3) + bi[t] + bh[t];
  __syncthreads();
  if(t < 64){
    float ig = sigmoidf_(gs[t]);
    float fg = sigmoidf_(gs[64+t]);
    float gg = tanhf(gs[128+t]);
    float og = sigmoidf_(gs[192+t]);
    float cn = fg*cv[t] + ig*gg;
    cv[t] = cn;
    hv[t] = og*tanhf(cn);
  }
  __syncthreads();
}

__global__ __launch_bounds__(256) void k_s2s(
    const float* __restrict__ x, const int* __restrict__ gid, int N,
    const float* __restrict__ t0ih, const float* __restrict__ t0hh,
    const float* __restrict__ l0_bih, const float* __restrict__ l0_bhh,
    const float* __restrict__ t12ih, const float* __restrict__ t12hh,
    const float* __restrict__ l12_bih, const float* __restrict__ l12_bhh,
    const float* __restrict__ W1, const float* __restrict__ b1,
    const float* __restrict__ W2, const float* __restrict__ b2,
    float* __restrict__ y)
{
  const int b = blockIdx.x;
  const int t = threadIdx.x;
  const int wave = t >> 6, lane = t & 63;
  __shared__ float xt[S2S_CAP*64];
  __shared__ float hsl[3][64], csl[3][64], qs[128], gs[256];
  __shared__ float ps[S2S_CAP], rop[4*64], wred[4], wsum[4];
  __shared__ int sh_n0, sh_n1;

  if(t == 0) sh_n0 = lbound(gid, N, b);
  if(t == 1) sh_n1 = lbound(gid, N, b+1);
  if(t < 192){ hsl[t>>6][t&63] = 0.f; csl[t>>6][t&63] = 0.f; }
  if(t < 128) qs[t] = 0.f;
  __syncthreads();
  const int n0 = sh_n0, cnt = sh_n1 - sh_n0;
  const int cc = (cnt < S2S_CAP) ? cnt : S2S_CAP;

  // cache node tile in LDS (read x once)
  for(int j = wave; j < cc; j += 4)
    xt[j*64 + lane] = x[(size_t)(n0+j)*64 + lane];
  __syncthreads();

  for(int step=0; step<S2S_STEPS; step++){
    lstm_layer<128>(qs,     hsl[0], csl[0], t0ih,           t0hh,           l0_bih,        l0_bhh,        gs, t);
    lstm_layer<64>(hsl[0],  hsl[1], csl[1], t12ih,          t12hh,          l12_bih,       l12_bhh,       gs, t);
    lstm_layer<64>(hsl[1],  hsl[2], csl[2], t12ih + 64*256, t12hh + 64*256, l12_bih + 256, l12_bhh + 256, gs, t);

    // ---- attention: pass 1 (dot + max), dots cached in ps ----
    float qv = hsl[2][lane];
    float pm = -1e30f;
    for(int j = wave; j < cc; j += 4){
      float p = xt[j*64 + lane] * qv;
#pragma unroll
      for(int o=32;o;o>>=1) p += __shfl_xor(p, o, 64);
      if(lane == 0) ps[j] = p;
      pm = fmaxf(pm, p);
    }
    for(int j = S2S_CAP + wave; j < cnt; j += 4){   // fallback (rare)
      float p = x[(size_t)(n0+j)*64 + lane] * qv;
#pragma unroll
      for(int o=32;o;o>>=1) p += __shfl_xor(p, o, 64);
      pm = fmaxf(pm, p);
    }
    if(lane == 0) wred[wave] = pm;
    __syncthreads();
    float mx = fmaxf(fmaxf(wred[0],wred[1]), fmaxf(wred[2],wred[3]));

    // ---- pass 2: exp/sum/weighted accumulate (LDS only for cached nodes) ----
    float pro = 0.f, pssum = 0.f;
    for(int j = wave; j < cc; j += 4){
      float ex = expf(ps[j] - mx);
      pssum += ex;
      pro = fmaf(ex, xt[j*64 + lane], pro);
    }
    for(int j = S2S_CAP + wave; j < cnt; j += 4){   // fallback (rare)
      float xv = x[(size_t)(n0+j)*64 + lane];
      float p = xv * qv;
#pragma unroll
      for(int o=32;o;o>>=1) p += __shfl_xor(p, o, 64);
      float ex = expf(p - mx);
      pssum += ex;
      pro = fmaf(ex, xv, pro);
    }
    rop[wave*64 + lane] = pro;
    if(lane == 0) wsum[wave] = pssum;
    __syncthreads();
    if(t < 64){
      float tot = wsum[0]+wsum[1]+wsum[2]+wsum[3];
      float inv = (tot > 0.f) ? 1.f/tot : 0.f;
      float rv = (rop[t] + rop[64+t] + rop[128+t] + rop[192+t]) * inv;
      qs[t] = hsl[2][t];
      qs[64+t] = rv;
    }
    __syncthreads();
  }
  // ---- head ----
  if(t < 64){
    float a = b1[t];
#pragma unroll 4
    for(int k=0;k<128;k++) a = fmaf(qs[k], W1[k*64+t], a);
    gs[t] = fmaxf(a, 0.f);
  }
  __syncthreads();
  if(t < 12){
    float o = b2[t];
#pragma unroll 4
    for(int k=0;k<64;k++) o = fmaf(gs[k], W2[k*12+t], o);
    y[b*12+t] = o;
  }
}

extern "C" void kernel_launch(void* const* d_in, const int* in_sizes, int n_in,
                              void* d_out, int out_size, void* d_ws, size_t ws_size,
                              hipStream_t stream) {
  const float* node_feat = (const float*)d_in[0];
  const float* edge_feat = (const float*)d_in[1];
  const int*   src       = (const int*)d_in[2];
  const int*   dst       = (const int*)d_in[3];
  const int*   gid       = (const int*)d_in[4];
  const float* lin0_W = (const float*)d_in[6];
  const float* lin0_b = (const float*)d_in[7];
  const float* em_W1  = (const float*)d_in[8];
  const float* em_b1  = (const float*)d_in[9];
  const float* em_W2  = (const float*)d_in[10];
  const float* em_b2  = (const float*)d_in[11];
  const float* conv_b = (const float*)d_in[12];
  const float* gru_Wih = (const float*)d_in[13];
  const float* gru_Whh = (const float*)d_in[14];
  const float* gru_bih = (const float*)d_in[15];
  const float* gru_bhh = (const float*)d_in[16];
  const float* l0_Wih = (const float*)d_in[17];
  const float* l0_Whh = (const float*)d_in[18];
  const float* l0_bih = (const float*)d_in[19];
  const float* l0_bhh = (const float*)d_in[20];
  const float* l12_Wih = (const float*)d_in[21];
  const float* l12_Whh = (const float*)d_in[22];
  const float* l12_bih = (const float*)d_in[23];
  const float* l12_bhh = (const float*)d_in[24];
  const float* lin1_W = (const float*)d_in[25];
  const float* lin1_b = (const float*)d_in[26];
  const float* lin2_W = (const float*)d_in[27];
  const float* lin2_b = (const float*)d_in[28];
  float* y = (float*)d_out;

  const int N = in_sizes[0] / 15;
  const int E = in_sizes[1] / 5;
  const int B = NGRAPH;

  char* p = (char*)d_ws;
  auto carve = [&](size_t bytes)->char* {
    char* r = p; p += (bytes + 255) & ~(size_t)255; return r;
  };
  _Float16* he_h = (_Float16*)carve((size_t)E*160*2);
  _Float16* W2T  = (_Float16*)carve((size_t)4096*160*2);
  float* x     = (float*)carve((size_t)N*64*4);
  float* agg   = (float*)carve((size_t)N*64*4);
  float* gWihT = (float*)carve(192*64*4);
  float* gWhhT = (float*)carve(192*64*4);
  float* t0ih  = (float*)carve(128*256*4);
  float* t0hh  = (float*)carve(64*256*4);
  float* t12ih = (float*)carve(2*64*256*4);
  float* t12hh = (float*)carve(2*64*256*4);
  (void)ws_size; (void)n_in; (void)out_size;

  // ---- prep ----
  k_lin0<<<(N+3)/4, 256, 0, stream>>>(node_feat, lin0_W, lin0_b, x, N);
  k_edgeh<<<E, 192, 0, stream>>>(edge_feat, em_W1, em_b1, he_h, E);
  k_prepW2<<<(4096*160+255)/256, 256, 0, stream>>>(em_W2, em_b2, W2T);
  k_tr_gru<<<(192*64+255)/256, 256, 0, stream>>>(gru_Wih, gru_Whh, gWihT, gWhhT);
  k_tr_lstm<<<(2*256*64+255)/256, 256, 0, stream>>>(l0_Wih, l0_Whh, l12_Wih, l12_Whh,
                                                    t0ih, t0hh, t12ih, t12hh);
  k_zero<<<(N*64+255)/256, 256, 0, stream>>>(agg, N*64);

  // ---- message passing (k_gru2 zeroes agg for the next step) ----
  const int nblk = (E + 63) / 64;
  for(int s=0; s<MP_STEPS; s++){
    k_fmsg<<<nblk, 256, 0, stream>>>(he_h, W2T, x, src, dst, agg, E);
    k_gru2<<<(N+31)/32, 256, 0, stream>>>(x, agg, conv_b, gWihT, gWhhT, gru_bih, gru_bhh, N);
  }

  // ---- fused set2set + head ----
  k_s2s<<<B, 256, 0, stream>>>(x, gid, N,
                               t0ih, t0hh, l0_bih, l0_bhh,
                               t12ih, t12hh, l12_bih, l12_bhh,
                               lin1_W, lin1_b, lin2_W, lin2_b, y);
}